// Round 5
// baseline (1652.019 us; speedup 1.0000x reference)
//
#include <hip/hip_runtime.h>
#include <hip/hip_fp16.h>
#include <cstdint>

// B=64, T=512, F=1024, U=256, G=4U=1024
#define BB 64
#define TT 512
#define FF 1024
#define UU 256
#define GG 1024

typedef _Float16 f16x8 __attribute__((ext_vector_type(8)));
typedef float f32x4 __attribute__((ext_vector_type(4)));

typedef union { uint4 u; f16x8 h; } pk16;

__device__ __forceinline__ float sigmf_(float x) { return 1.f / (1.f + __expf(-x)); }
__device__ __forceinline__ float tanhf_(float x) { return 1.f - 2.f / (1.f + __expf(2.f * x)); }

__device__ __forceinline__ uint32_t packh2(float lo, float hi) {
  __half2 h = __floats2half2_rn(lo, hi);
  return *reinterpret_cast<uint32_t*>(&h);
}

// ---------------- mask kernel: mask[b,t] = any(x[b,t,:] != 0) ----------------
__global__ __launch_bounds__(256) void mask_kernel(const float* __restrict__ x,
                                                   float* __restrict__ maskF) {
  int row = blockIdx.x;
  int tid = threadIdx.x;
  const float4* xr = (const float4*)(x + (size_t)row * FF);
  float4 v = xr[tid];
  bool nz = (v.x != 0.f) || (v.y != 0.f) || (v.z != 0.f) || (v.w != 0.f);
  __shared__ int flag;
  if (tid == 0) flag = 0;
  __syncthreads();
  if (__any(nz)) {
    if ((tid & 63) == 0) atomicOr(&flag, 1);
  }
  __syncthreads();
  if (tid == 0) maskF[row] = flag ? 1.f : 0.f;
}

// -------- pack W_h (256x1024 f32, [u][c]) -> whB [1024 cols][256 k] f16 ------
__global__ __launch_bounds__(256) void pack_whB(const float* __restrict__ Wh,
                                                __half* __restrict__ whB) {
  int col = blockIdx.x;   // 0..1023
  int k = threadIdx.x;    // 0..255
  whB[col * 256 + k] = __float2half(Wh[(size_t)k * GG + col]);
}

// ---------------- MFMA GEMM: C(f16) = [relu](A @ B + bias) -------------------
// A: M x K (row-major, TA = float or __half), B: K x N (row-major f32)
// tile 128(M) x 64(N), BK=32, 256 threads = 4 waves (2x2 wave grid)
template <typename TA, bool RELU>
__global__ __launch_bounds__(256) void gemm16(const TA* __restrict__ A,
                                              const float* __restrict__ Bm,
                                              const float* __restrict__ bias,
                                              __half* __restrict__ C,
                                              int M, int N, int K) {
  __shared__ _Float16 As[128][40];
  __shared__ _Float16 Bs[64][40];
  int tid = threadIdx.x;
  int lane = tid & 63, w = tid >> 6;
  int wm = w & 1, wn = w >> 1;
  int m0 = blockIdx.x * 128, n0 = blockIdx.y * 64;
  int fr = lane & 15, ks = lane >> 4;

  f32x4 acc[4][2];
#pragma unroll
  for (int i = 0; i < 4; ++i)
#pragma unroll
    for (int j = 0; j < 2; ++j) acc[i][j] = (f32x4){0.f, 0.f, 0.f, 0.f};

  for (int k0 = 0; k0 < K; k0 += 32) {
    {
      int r = tid >> 3, kq = (tid & 7) * 4;
#pragma unroll
      for (int i = 0; i < 4; ++i) {
        int row = r + 32 * i;
        const TA* src = A + (size_t)(m0 + row) * K + k0 + kq;
        if constexpr (sizeof(TA) == 4) {
          float4 v = *reinterpret_cast<const float4*>(src);
          union { uint2 u; _Float16 h[4]; } pk;
          pk.h[0] = (_Float16)v.x; pk.h[1] = (_Float16)v.y;
          pk.h[2] = (_Float16)v.z; pk.h[3] = (_Float16)v.w;
          *reinterpret_cast<uint2*>(&As[row][kq]) = pk.u;
        } else {
          uint2 v = *reinterpret_cast<const uint2*>(src);
          *reinterpret_cast<uint2*>(&As[row][kq]) = v;
        }
      }
      int nn = tid & 63, kb = tid >> 6;
#pragma unroll
      for (int i = 0; i < 8; ++i) {
        int kk = kb + 4 * i;
        Bs[nn][kk] = (_Float16)Bm[(size_t)(k0 + kk) * N + n0 + nn];
      }
    }
    __syncthreads();
    f16x8 af[4], bf[2];
#pragma unroll
    for (int fm = 0; fm < 4; ++fm)
      af[fm] = *reinterpret_cast<const f16x8*>(&As[wm * 64 + fm * 16 + fr][ks * 8]);
#pragma unroll
    for (int fn = 0; fn < 2; ++fn)
      bf[fn] = *reinterpret_cast<const f16x8*>(&Bs[wn * 32 + fn * 16 + fr][ks * 8]);
#pragma unroll
    for (int fm = 0; fm < 4; ++fm)
#pragma unroll
      for (int fn = 0; fn < 2; ++fn)
        acc[fm][fn] = __builtin_amdgcn_mfma_f32_16x16x32_f16(af[fm], bf[fn], acc[fm][fn], 0, 0, 0);
    __syncthreads();
  }
#pragma unroll
  for (int fm = 0; fm < 4; ++fm)
#pragma unroll
    for (int fn = 0; fn < 2; ++fn) {
      int mg0 = m0 + wm * 64 + fm * 16 + ks * 4;
      int ng = n0 + wn * 32 + fn * 16 + fr;
      float bv = bias[ng];
#pragma unroll
      for (int r = 0; r < 4; ++r) {
        float v = acc[fm][fn][r] + bv;
        if constexpr (RELU) v = fmaxf(v, 0.f);
        C[(size_t)(mg0 + r) * N + ng] = __float2half(v);
      }
    }
}

// ---------------- recurrence: MFMA GEMV, one block per batch -----------------
// 1024 threads = 16 waves. __launch_bounds__(1024, 1): CUDA semantics, min
// 1 BLOCK per CU -> 16 waves/CU = 4/SIMD -> 128-VGPR budget. Weight residency
// (96 VGPRs) + working set (~28) fits by design; R1-R4 showed any plan that
// needs >128 gets spilled/rematerialized.
// Wave w owns gate cols [w*64, w*64+64) as 4 col-tiles of 16.
// W_h f16 [col][k]: k-tiles 0..5 in registers (24 B-frags, asm-pinned),
// k-tiles 6..7 streamed from LDS each step (128KB, linear conflict-free b128).
// h packed in 512B LDS (hpk); A-frags broadcast from it; MFMA M=1.
__global__ void __launch_bounds__(1024, 1)
lstm_rec(const __half* __restrict__ whB,   // [1024][256] f16
         const __half* __restrict__ zxh,   // [B*T][1024]
         const float* __restrict__ maskF,  // [B*T]
         const float* __restrict__ Wp,     // [256]
         const float* __restrict__ bp,     // [1]
         float* __restrict__ out)          // [B*T]
{
  __shared__ uint4 ldsW4[8 * 1024];               // 128KB [slot][wave][lane]
  __shared__ float gbuf[GG];                      // 4KB
  __shared__ __align__(16) uint32_t hpk[UU / 2];  // 512B
  __shared__ float red[4];

  const int b = blockIdx.x;
  const int t = threadIdx.x;
  const int lane = t & 63, w = t >> 6;
  const int fr = lane & 15, q = lane >> 4;

  const uint4* whB4 = (const uint4*)whB;  // uint4 idx = col*32 + kt*4 + q

  // --- preload register B-frags: kt=0..5, ct=0..3 (96 VGPRs) ---
  pk16 bfr[6][4];
#pragma unroll
  for (int kt = 0; kt < 6; ++kt)
#pragma unroll
    for (int ct = 0; ct < 4; ++ct) {
      int col = w * 64 + ct * 16 + fr;
      bfr[kt][ct].u = whB4[col * 32 + kt * 4 + q];
    }
  // --- fill LDS with kt=6,7 ---
#pragma unroll
  for (int kt6 = 0; kt6 < 2; ++kt6)
#pragma unroll
    for (int ct = 0; ct < 4; ++ct) {
      int col = w * 64 + ct * 16 + fr;
      ldsW4[(kt6 * 4 + ct) * 1024 + w * 64 + lane] = whB4[col * 32 + (6 + kt6) * 4 + q];
    }
  // Pin B-frags live (forbid remat of the global loads inside the loop).
#pragma unroll
  for (int kt = 0; kt < 6; ++kt)
#pragma unroll
    for (int ct = 0; ct < 4; ++ct)
      asm volatile("" : "+v"(bfr[kt][ct].u.x), "+v"(bfr[kt][ct].u.y),
                        "+v"(bfr[kt][ct].u.z), "+v"(bfr[kt][ct].u.w));

  if (t < UU / 2) hpk[t] = 0u;
  float c_state = 0.f, h_state = 0.f;
  float wp = (t < UU) ? Wp[t] : 0.f;
  float bpv = bp[0];
  __syncthreads();

  const __half* zp = zxh + (size_t)b * TT * GG;
  const float* mrow = maskF + b * TT;
  float* outp = out + b * TT;
  const uint4* hp4 = (const uint4*)hpk;     // idx = kt*4 + q
  const uint4* lw = ldsW4 + w * 64 + lane;  // slot s at lw[s*1024]

  for (int step = 0; step < TT; ++step) {
    // prefetch cell-phase operands (latency hides under the MFMA phase)
    __half zx_i{}, zx_f{}, zx_g{}, zx_o{};
    float mval = 0.f;
    if (t < UU) {
      zx_i = zp[t];
      zx_f = zp[t + 256];
      zx_g = zp[t + 512];
      zx_o = zp[t + 768];
      mval = mrow[step];
    }

    // ---- phase A: gates(h) = h @ W_h via MFMA ----
    f32x4 d0 = {0.f, 0.f, 0.f, 0.f}, d1 = d0, d2 = d0, d3 = d0;
#pragma unroll
    for (int kt = 0; kt < 8; ++kt) {
      pk16 a;
      a.u = hp4[kt * 4 + q];
      pk16 w0, w1, w2, w3;
      if (kt < 6) {
        w0 = bfr[kt][0]; w1 = bfr[kt][1]; w2 = bfr[kt][2]; w3 = bfr[kt][3];
      } else {
        int s = (kt - 6) * 4;
        w0.u = lw[(s + 0) * 1024];
        w1.u = lw[(s + 1) * 1024];
        w2.u = lw[(s + 2) * 1024];
        w3.u = lw[(s + 3) * 1024];
      }
      d0 = __builtin_amdgcn_mfma_f32_16x16x32_f16(a.h, w0.h, d0, 0, 0, 0);
      d1 = __builtin_amdgcn_mfma_f32_16x16x32_f16(a.h, w1.h, d1, 0, 0, 0);
      d2 = __builtin_amdgcn_mfma_f32_16x16x32_f16(a.h, w2.h, d2, 0, 0, 0);
      d3 = __builtin_amdgcn_mfma_f32_16x16x32_f16(a.h, w3.h, d3, 0, 0, 0);
    }
    if (lane < 16) {  // D row 0 lives in lanes 0..15, reg 0
      gbuf[w * 64 + lane] = d0[0];
      gbuf[w * 64 + 16 + lane] = d1[0];
      gbuf[w * 64 + 32 + lane] = d2[0];
      gbuf[w * 64 + 48 + lane] = d3[0];
    }
    __syncthreads();

    // ---- phase B: cell update (threads 0..255), h-repack, out-projection ----
    if (t < UU) {
      float gi = gbuf[t] + __half2float(zx_i);
      float gf = gbuf[t + 256] + __half2float(zx_f);
      float gg = gbuf[t + 512] + __half2float(zx_g);
      float go = gbuf[t + 768] + __half2float(zx_o);
      float ig = sigmf_(gi);
      float fg = sigmf_(gf);
      float g_ = tanhf_(gg);
      float og = sigmf_(go);
      float cn = fg * c_state + ig * g_;
      float hn = og * tanhf_(cn);
      bool on = (mval > 0.5f);
      c_state = on ? cn : c_state;
      h_state = on ? hn : h_state;
      float hnbr = __shfl_down(h_state, 1);
      if (!(t & 1)) hpk[t >> 1] = packh2(h_state, hnbr);
      float pp = h_state * wp;
#pragma unroll
      for (int off = 32; off > 0; off >>= 1) pp += __shfl_down(pp, off);
      if ((t & 63) == 0) red[t >> 6] = pp;
    }
    __syncthreads();
    if (t == 0) {
      float s = red[0] + red[1] + red[2] + red[3] + bpv;
      outp[step] = 1.f / (1.f + __expf(-s));
    }
    zp += GG;
  }
}

extern "C" void kernel_launch(void* const* d_in, const int* in_sizes, int n_in,
                              void* d_out, int out_size, void* d_ws, size_t ws_size,
                              hipStream_t stream) {
  const float* x = (const float*)d_in[0];
  const float* Wfc = (const float*)d_in[1];
  const float* bfc = (const float*)d_in[2];
  const float* Wx = (const float*)d_in[3];
  const float* Wh = (const float*)d_in[4];
  const float* blstm = (const float*)d_in[5];
  const float* Wp = (const float*)d_in[6];
  const float* bp = (const float*)d_in[7];
  float* out = (float*)d_out;

  char* ws = (char*)d_ws;
  float* maskF = (float*)(ws);                                    // 128 KB
  __half* zh = (__half*)(ws + 131072);                            // 16.78 MB
  __half* zxh = (__half*)(ws + 131072 + 16777216);                // 67.1 MB
  __half* whB = (__half*)(ws + 131072 + 16777216 + 67108864);     // 512 KB

  mask_kernel<<<BB * TT, 256, 0, stream>>>(x, maskF);
  pack_whB<<<GG, 256, 0, stream>>>(Wh, whB);
  gemm16<float, true><<<dim3((BB * TT) / 128, UU / 64), 256, 0, stream>>>(
      x, Wfc, bfc, zh, BB * TT, UU, FF);
  gemm16<__half, false><<<dim3((BB * TT) / 128, GG / 64), 256, 0, stream>>>(
      zh, Wx, blstm, zxh, BB * TT, GG, UU);
  lstm_rec<<<BB, 1024, 0, stream>>>(whB, zxh, maskF, Wp, bp, out);
}

// Round 6
// 1076.263 us; speedup vs baseline: 1.5350x; 1.5350x over previous
//
#include <hip/hip_runtime.h>
#include <hip/hip_fp16.h>
#include <hip/hip_fp8.h>
#include <cstdint>

// B=64, T=512, F=1024, U=256, G=4U=1024
#define BB 64
#define TT 512
#define FF 1024
#define UU 256
#define GG 1024

typedef _Float16 f16x8 __attribute__((ext_vector_type(8)));
typedef float f32x4 __attribute__((ext_vector_type(4)));

typedef union { uint4 u; f16x8 h; } pk16;
typedef union { uint2 u; long long l; } pk8;   // 8 fp8 = one MFMA operand (2 VGPRs)

__device__ __forceinline__ float sigmf_(float x) { return 1.f / (1.f + __expf(-x)); }
__device__ __forceinline__ float tanhf_(float x) { return 1.f - 2.f / (1.f + __expf(2.f * x)); }

// ---------------- mask kernel: mask[b,t] = any(x[b,t,:] != 0) ----------------
__global__ __launch_bounds__(256) void mask_kernel(const float* __restrict__ x,
                                                   float* __restrict__ maskF) {
  int row = blockIdx.x;
  int tid = threadIdx.x;
  const float4* xr = (const float4*)(x + (size_t)row * FF);
  float4 v = xr[tid];
  bool nz = (v.x != 0.f) || (v.y != 0.f) || (v.z != 0.f) || (v.w != 0.f);
  __shared__ int flag;
  if (tid == 0) flag = 0;
  __syncthreads();
  if (__any(nz)) {
    if ((tid & 63) == 0) atomicOr(&flag, 1);
  }
  __syncthreads();
  if (tid == 0) maskF[row] = flag ? 1.f : 0.f;
}

// ---- pack W_h (256x1024 f32, [u][c]) -> whP [1024 cols][256 k] fp8 e4m3 -----
// Scaled by 16 (values land in e4m3's normal range); undone by 0.0625 in rec.
__global__ __launch_bounds__(256) void pack_whP(const float* __restrict__ Wh,
                                                uint8_t* __restrict__ whP) {
  int col = blockIdx.x;   // 0..1023
  int k = threadIdx.x;    // 0..255
  __hip_fp8_e4m3 f(Wh[(size_t)k * GG + col] * 16.f);
  whP[col * 256 + k] = (uint8_t)f.__x;
}

// ---------------- MFMA GEMM: C(f16) = [relu](A @ B + bias) -------------------
// A: M x K (row-major, TA = float or __half), B: K x N (row-major f32)
// tile 128(M) x 64(N), BK=32, 256 threads = 4 waves (2x2 wave grid)
template <typename TA, bool RELU>
__global__ __launch_bounds__(256) void gemm16(const TA* __restrict__ A,
                                              const float* __restrict__ Bm,
                                              const float* __restrict__ bias,
                                              __half* __restrict__ C,
                                              int M, int N, int K) {
  __shared__ _Float16 As[128][40];
  __shared__ _Float16 Bs[64][40];
  int tid = threadIdx.x;
  int lane = tid & 63, w = tid >> 6;
  int wm = w & 1, wn = w >> 1;
  int m0 = blockIdx.x * 128, n0 = blockIdx.y * 64;
  int fr = lane & 15, ks = lane >> 4;

  f32x4 acc[4][2];
#pragma unroll
  for (int i = 0; i < 4; ++i)
#pragma unroll
    for (int j = 0; j < 2; ++j) acc[i][j] = (f32x4){0.f, 0.f, 0.f, 0.f};

  for (int k0 = 0; k0 < K; k0 += 32) {
    {
      int r = tid >> 3, kq = (tid & 7) * 4;
#pragma unroll
      for (int i = 0; i < 4; ++i) {
        int row = r + 32 * i;
        const TA* src = A + (size_t)(m0 + row) * K + k0 + kq;
        if constexpr (sizeof(TA) == 4) {
          float4 v = *reinterpret_cast<const float4*>(src);
          union { uint2 u; _Float16 h[4]; } pk;
          pk.h[0] = (_Float16)v.x; pk.h[1] = (_Float16)v.y;
          pk.h[2] = (_Float16)v.z; pk.h[3] = (_Float16)v.w;
          *reinterpret_cast<uint2*>(&As[row][kq]) = pk.u;
        } else {
          uint2 v = *reinterpret_cast<const uint2*>(src);
          *reinterpret_cast<uint2*>(&As[row][kq]) = v;
        }
      }
      int nn = tid & 63, kb = tid >> 6;
#pragma unroll
      for (int i = 0; i < 8; ++i) {
        int kk = kb + 4 * i;
        Bs[nn][kk] = (_Float16)Bm[(size_t)(k0 + kk) * N + n0 + nn];
      }
    }
    __syncthreads();
    f16x8 af[4], bf[2];
#pragma unroll
    for (int fm = 0; fm < 4; ++fm)
      af[fm] = *reinterpret_cast<const f16x8*>(&As[wm * 64 + fm * 16 + fr][ks * 8]);
#pragma unroll
    for (int fn = 0; fn < 2; ++fn)
      bf[fn] = *reinterpret_cast<const f16x8*>(&Bs[wn * 32 + fn * 16 + fr][ks * 8]);
#pragma unroll
    for (int fm = 0; fm < 4; ++fm)
#pragma unroll
      for (int fn = 0; fn < 2; ++fn)
        acc[fm][fn] = __builtin_amdgcn_mfma_f32_16x16x32_f16(af[fm], bf[fn], acc[fm][fn], 0, 0, 0);
    __syncthreads();
  }
#pragma unroll
  for (int fm = 0; fm < 4; ++fm)
#pragma unroll
    for (int fn = 0; fn < 2; ++fn) {
      int mg0 = m0 + wm * 64 + fm * 16 + ks * 4;
      int ng = n0 + wn * 32 + fn * 16 + fr;
      float bv = bias[ng];
#pragma unroll
      for (int r = 0; r < 4; ++r) {
        float v = acc[fm][fn][r] + bv;
        if constexpr (RELU) v = fmaxf(v, 0.f);
        C[(size_t)(mg0 + r) * N + ng] = __float2half(v);
      }
    }
}

// ---------------- recurrence: fp8 MFMA GEMV, one block per batch -------------
// 1024 threads = 16 waves. Empirical arch-VGPR cap = 65536/blocksize = 64;
// this design NEEDS only ~50 VGPR + 16 acc: W_h fp8 [col][k] (x16 scaled),
// k-tiles 0..3 in regs (16 frags x 2 VGPR = 32), k-tiles 4..7 in LDS (128KB,
// stride-1 conflict-free ds_read_b64). h is re-quantized to fp8 each step
// into 256B of LDS; A-frags are 16-lane broadcasts of it; MFMA M=1.
__global__ void __launch_bounds__(1024, 1)
lstm_rec(const uint8_t* __restrict__ whP,   // [1024][256] fp8 (x16)
         const __half* __restrict__ zxh,    // [B*T][1024]
         const float* __restrict__ maskF,   // [B*T]
         const float* __restrict__ Wp,      // [256]
         const float* __restrict__ bp,      // [1]
         float* __restrict__ out)           // [B*T]
{
  __shared__ uint2 ldsW2[16 * 1024];              // 128KB [slot][tid]
  __shared__ float gbuf[GG];                      // 4KB
  __shared__ __align__(8) uint32_t hpk[UU / 4];   // 256B fp8 h
  __shared__ float red[4];

  const int b = blockIdx.x;
  const int t = threadIdx.x;
  const int lane = t & 63, w = t >> 6;
  const int fr = lane & 15, q = lane >> 4;

  const uint2* whP2 = (const uint2*)whP;  // uint2 idx = col*32 + kt*4 + q

  // --- preload register B-frags: kt=0..3, ct=0..3 (32 VGPRs) ---
  pk8 bfr[4][4];
#pragma unroll
  for (int kt = 0; kt < 4; ++kt)
#pragma unroll
    for (int ct = 0; ct < 4; ++ct) {
      int col = w * 64 + ct * 16 + fr;
      bfr[kt][ct].u = whP2[col * 32 + kt * 4 + q];
    }
  // --- fill LDS with kt=4..7 (each thread stores exactly what it reads) ---
#pragma unroll
  for (int kt = 4; kt < 8; ++kt)
#pragma unroll
    for (int ct = 0; ct < 4; ++ct) {
      int col = w * 64 + ct * 16 + fr;
      ldsW2[((kt - 4) * 4 + ct) * 1024 + t] = whP2[col * 32 + kt * 4 + q];
    }
  // Pin reg frags live (forbid remat of the global loads inside the loop).
#pragma unroll
  for (int kt = 0; kt < 4; ++kt)
#pragma unroll
    for (int ct = 0; ct < 4; ++ct)
      asm volatile("" : "+v"(bfr[kt][ct].u.x), "+v"(bfr[kt][ct].u.y));

  if (t < UU / 4) hpk[t] = 0u;
  float c_state = 0.f, h_state = 0.f;
  float wp = (t < UU) ? Wp[t] : 0.f;
  float bpv = bp[0];
  __syncthreads();

  const __half* zp = zxh + (size_t)b * TT * GG;
  const float* mrow = maskF + b * TT;
  float* outp = out + b * TT;
  const uint2* hp2 = (const uint2*)hpk;  // idx = kt*4 + q

  for (int step = 0; step < TT; ++step) {
    // prefetch cell-phase operands (latency hides under the MFMA phase)
    __half zx_i{}, zx_f{}, zx_g{}, zx_o{};
    float mval = 0.f;
    if (t < UU) {
      zx_i = zp[t];
      zx_f = zp[t + 256];
      zx_g = zp[t + 512];
      zx_o = zp[t + 768];
      mval = mrow[step];
    }

    // ---- phase A: gates(h) = h @ W_h via fp8 MFMA ----
    f32x4 d0 = {0.f, 0.f, 0.f, 0.f}, d1 = d0, d2 = d0, d3 = d0;
#pragma unroll
    for (int kt = 0; kt < 8; ++kt) {
      pk8 a;
      a.u = hp2[kt * 4 + q];
      pk8 w0, w1, w2, w3;
      if (kt < 4) {
        w0 = bfr[kt][0]; w1 = bfr[kt][1]; w2 = bfr[kt][2]; w3 = bfr[kt][3];
      } else {
        int s = (kt - 4) * 4;
        w0.u = ldsW2[(s + 0) * 1024 + t];
        w1.u = ldsW2[(s + 1) * 1024 + t];
        w2.u = ldsW2[(s + 2) * 1024 + t];
        w3.u = ldsW2[(s + 3) * 1024 + t];
      }
      d0 = __builtin_amdgcn_mfma_f32_16x16x32_fp8_fp8(a.l, w0.l, d0, 0, 0, 0);
      d1 = __builtin_amdgcn_mfma_f32_16x16x32_fp8_fp8(a.l, w1.l, d1, 0, 0, 0);
      d2 = __builtin_amdgcn_mfma_f32_16x16x32_fp8_fp8(a.l, w2.l, d2, 0, 0, 0);
      d3 = __builtin_amdgcn_mfma_f32_16x16x32_fp8_fp8(a.l, w3.l, d3, 0, 0, 0);
    }
    if (lane < 16) {  // D row 0 lives in lanes 0..15, reg 0
      gbuf[w * 64 + lane] = d0[0];
      gbuf[w * 64 + 16 + lane] = d1[0];
      gbuf[w * 64 + 32 + lane] = d2[0];
      gbuf[w * 64 + 48 + lane] = d3[0];
    }
    __syncthreads();

    // ---- phase B: cell update (threads 0..255), h->fp8 repack, projection ---
    if (t < UU) {
      float gi = fmaf(gbuf[t], 0.0625f, __half2float(zx_i));
      float gf = fmaf(gbuf[t + 256], 0.0625f, __half2float(zx_f));
      float gg = fmaf(gbuf[t + 512], 0.0625f, __half2float(zx_g));
      float go = fmaf(gbuf[t + 768], 0.0625f, __half2float(zx_o));
      float ig = sigmf_(gi);
      float fg = sigmf_(gf);
      float g_ = tanhf_(gg);
      float og = sigmf_(go);
      float cn = fg * c_state + ig * g_;
      float hn = og * tanhf_(cn);
      bool on = (mval > 0.5f);
      c_state = on ? cn : c_state;
      h_state = on ? hn : h_state;
      // h -> fp8, gather 4 bytes per u32 via intra-wave shuffles
      __hip_fp8_e4m3 f8(h_state);
      uint32_t hb = (uint32_t)f8.__x;
      hb |= __shfl_down(hb, 1) << 8;
      hb |= __shfl_down(hb, 2) << 16;
      if ((t & 3) == 0) hpk[t >> 2] = hb;
      float pp = h_state * wp;
#pragma unroll
      for (int off = 32; off > 0; off >>= 1) pp += __shfl_down(pp, off);
      if ((t & 63) == 0) red[t >> 6] = pp;
    }
    __syncthreads();
    if (t == 0) {
      float s = red[0] + red[1] + red[2] + red[3] + bpv;
      outp[step] = 1.f / (1.f + __expf(-s));
    }
    zp += GG;
  }
}

extern "C" void kernel_launch(void* const* d_in, const int* in_sizes, int n_in,
                              void* d_out, int out_size, void* d_ws, size_t ws_size,
                              hipStream_t stream) {
  const float* x = (const float*)d_in[0];
  const float* Wfc = (const float*)d_in[1];
  const float* bfc = (const float*)d_in[2];
  const float* Wx = (const float*)d_in[3];
  const float* Wh = (const float*)d_in[4];
  const float* blstm = (const float*)d_in[5];
  const float* Wp = (const float*)d_in[6];
  const float* bp = (const float*)d_in[7];
  float* out = (float*)d_out;

  char* ws = (char*)d_ws;
  float* maskF = (float*)(ws);                                   // 128 KB
  __half* zh = (__half*)(ws + 131072);                           // 16.78 MB
  __half* zxh = (__half*)(ws + 131072 + 16777216);               // 67.1 MB
  uint8_t* whP = (uint8_t*)(ws + 131072 + 16777216 + 67108864);  // 256 KB

  mask_kernel<<<BB * TT, 256, 0, stream>>>(x, maskF);
  pack_whP<<<GG, 256, 0, stream>>>(Wh, whP);
  gemm16<float, true><<<dim3((BB * TT) / 128, UU / 64), 256, 0, stream>>>(
      x, Wfc, bfc, zh, BB * TT, UU, FF);
  gemm16<__half, false><<<dim3((BB * TT) / 128, GG / 64), 256, 0, stream>>>(
      zh, Wx, blstm, zxh, BB * TT, GG, UU);
  lstm_rec<<<BB, 1024, 0, stream>>>(whP, zxh, maskF, Wp, bp, out);
}